// Round 5
// baseline (3391.896 us; speedup 1.0000x reference)
//
#include <hip/hip_runtime.h>
#include <math.h>

#define DEVFN __device__ __forceinline__

typedef short  s16x8 __attribute__((ext_vector_type(8)));
typedef float  f32x4 __attribute__((ext_vector_type(4)));

constexpr int C     = 768;
constexpr int NROWS = 25216;   // 197*128
constexpr int NCL   = 128;     // class rows (features[0:1])
constexpr int KCB   = 4096;    // codes per codebook
constexpr int KOUT  = 8192;    // distance columns (class | feat)
constexpr int TK    = 3;
constexpr int NT    = 24;      // K-steps (768/32)
constexpr int MT    = 197;     // row tiles
constexpr int NTL   = 32;      // col tiles per codebook

// output layout (flat, return order)
constexpr long long QUANT_OFF  = 1;
constexpr long long QUANT_SZ   = (long long)NROWS * TK * C;         // 58,097,664
constexpr long long CLPERP_OFF = QUANT_OFF + QUANT_SZ;
constexpr long long FTPERP_OFF = CLPERP_OFF + 1;
constexpr long long CLAVG_OFF  = FTPERP_OFF + 1;
constexpr long long FTAVG_OFF  = CLAVG_OFF + KCB;
constexpr long long ENC_OFF    = FTAVG_OFF + KCB;
constexpr long long DIST_OFF   = ENC_OFF + (long long)NROWS * TK;   // 58,181,507

// packed pre-split bf16 scratch + top-3 partials (all live in the quant
// output region, which is written only later by gather_kernel; ~141 MB
// needed, 232 MB available)
constexpr size_t XS_ELE = (size_t)MT * NT * 4096;       // 19,365,888 bf16 per plane
constexpr size_t ES_ELE = (size_t)2 * NTL * NT * 4096;  //  6,291,456 bf16 per plane
constexpr size_t PV_ELE = (size_t)NROWS * 64 * 3;       //  4,841,472 (val or idx)

constexpr float FMAXV = 3.4028234663852886e38f;
// Padding value: largest float that stays FINITE through a bf16 round-trip
// (0x7F7F0000). FLT_MAX rounds to +inf in bf16 -> inf-inf = nan in the
// harness compare.
constexpr float PADV  = 3.3895313892515355e38f;

DEVFN void gload_lds16(const void* g, void* l) {
    __builtin_amdgcn_global_load_lds(
        (const __attribute__((address_space(1))) unsigned*)g,
        (__attribute__((address_space(3))) unsigned*)l, 16, 0, 0);
}

// ---------------- top-3 primitives ----------------
DEVFN bool better(float v, int i, float bv, int bi) {
    return (v < bv) || (v == bv && i < bi);  // stable: smaller index wins ties
}
DEVFN void ins3(float v, int i, float& v0, int& i0, float& v1, int& i1, float& v2, int& i2) {
    if (better(v, i, v2, i2)) {
        if (better(v, i, v0, i0)) { v2 = v1; i2 = i1; v1 = v0; i1 = i0; v0 = v; i0 = i; }
        else if (better(v, i, v1, i1)) { v2 = v1; i2 = i1; v1 = v; i1 = i; }
        else { v2 = v; i2 = i; }
    }
}

// ---------------- init ----------------
__global__ void init_kernel(float* counts) {
    int i = blockIdx.x * blockDim.x + threadIdx.x;
    if (i < KOUT) counts[i] = 0.0f;
}

// ---------------- row norms (features + both codebooks) ----------------
__global__ void norms_kernel(const float* __restrict__ X,
                             const float* __restrict__ CE,
                             const float* __restrict__ FE,
                             float* __restrict__ xnorm,
                             float* __restrict__ enorm) {
    int row  = blockIdx.x * 4 + (threadIdx.x >> 6);
    int lane = threadIdx.x & 63;
    const int TOT = NROWS + 2 * KCB;
    if (row >= TOT) return;
    const float* src; float* dst;
    if (row < NROWS) { src = X + (long long)row * C; dst = xnorm + row; }
    else {
        int r = row - NROWS;
        src = (r < KCB) ? (CE + (long long)r * C) : (FE + (long long)(r - KCB) * C);
        dst = enorm + r;   // [0..4095] class, [4096..8191] feat
    }
    const float4* p = (const float4*)src;
    float s = 0.f;
    for (int j = lane; j < C / 4; j += 64) {
        float4 v = p[j];
        s += v.x*v.x + v.y*v.y + v.z*v.z + v.w*v.w;
    }
    for (int o = 32; o > 0; o >>= 1) s += __shfl_down(s, o);
    if (lane == 0) *dst = s;
}

// ---------------- pre-split: fp32 -> packed swizzled bf16 hi/lo tiles ------
__global__ __launch_bounds__(256)
void presplit_kernel(const float* __restrict__ X,
                     const float* __restrict__ CE,
                     const float* __restrict__ FE,
                     short* __restrict__ XsH, short* __restrict__ XsL,
                     short* __restrict__ EsH, short* __restrict__ EsL) {
    const int b = blockIdx.x;                    // 0..(197*24 + 2*32*24 - 1)
    const float* src; char* dH; char* dL;
    if (b < MT * NT) {
        const int tile = b / NT, ks = b % NT;
        src = X + (size_t)tile * 128 * C + ks * 32;
        dH = (char*)(XsH + (size_t)b * 4096);
        dL = (char*)(XsL + (size_t)b * 4096);
    } else {
        const int bb = b - MT * NT;              // 0..1535
        const int book = bb / (NTL * NT);
        const int rem  = bb % (NTL * NT);
        const int tile = rem / NT, ks = rem % NT;
        src = (book ? FE : CE) + (size_t)tile * 128 * C + ks * 32;
        dH = (char*)(EsH + (size_t)bb * 4096);
        dL = (char*)(EsL + (size_t)bb * 4096);
    }
    const int tid = threadIdx.x;
    const int row = tid >> 2, oc = tid & 3;      // rows {row, row+64}, k-octet oc
    #pragma unroll
    for (int rr = 0; rr < 2; ++rr) {
        const int r = row + rr * 64;
        const float* s = src + (size_t)r * C + oc * 8;
        float4 v0 = *(const float4*)s;
        float4 v1 = *(const float4*)(s + 4);
        float f[8] = {v0.x, v0.y, v0.z, v0.w, v1.x, v1.y, v1.z, v1.w};
        s16x8 hi, lo;
        #pragma unroll
        for (int q = 0; q < 8; ++q) {
            unsigned u = __float_as_uint(f[q]);
            hi[q] = (short)(u >> 16);
            lo[q] = (short)(__float_as_uint(f[q] - __uint_as_float(u & 0xffff0000u)) >> 16);
        }
        const int off = (r * 64 + oc * 16) ^ ((r & 7) << 4);
        *(s16x8*)(dH + off) = hi;
        *(s16x8*)(dL + off) = lo;
    }
}

// ---------------- distance GEMM via bf16x3 MFMA + fused per-half top-3 -----
// D = (xn + en) - 2*X@E^T. dist is written (output) but never re-read:
// per row, each wave computes sorted top-3 over its 64 columns from
// registers and writes (val,idx) partials; topk_merge reduces 64 halves.
__global__ __launch_bounds__(256)
void gemm_dist_kernel(const short* __restrict__ XsH, const short* __restrict__ XsL,
                      const short* __restrict__ EsH, const short* __restrict__ EsL,
                      const float* __restrict__ xnorm,
                      const float* __restrict__ enorm,
                      float* __restrict__ dist,
                      float* __restrict__ pval,
                      int* __restrict__ pidx) {
    __shared__ __align__(16) char smem[2 * 4 * 8192];   // [buf][plane][8KB]

    // XCD-aware bijective swizzle: 6304 blocks, 6304 % 8 == 0, chunk = 788
    const int orig = blockIdx.y * gridDim.x + blockIdx.x;
    const int wg   = (orig & 7) * 788 + (orig >> 3);
    const int mt = wg >> 5, nt = wg & 31;

    const int m0 = mt * 128, n0 = nt * 128;
    const int colbase = (mt == 0) ? 0 : KCB;
    const int btile = ((mt == 0) ? 0 : NTL) + nt;
    const int tid = threadIdx.x, l = tid & 63, w = tid >> 6;
    const int wy = w >> 1, wx = w & 1;

    const char* gsrc[4] = {
        (const char*)XsH + (size_t)mt * NT * 8192,
        (const char*)XsL + (size_t)mt * NT * 8192,
        (const char*)EsH + (size_t)btile * NT * 8192,
        (const char*)EsL + (size_t)btile * NT * 8192
    };

    // fragment geometry: wave (wy,wx) owns a 64x64 sub-tile
    const int arow = wy * 64 + (l & 15);
    const int brow = wx * 64 + (l & 15);
    const int abase = (arow * 64 + ((l >> 4) * 16)) ^ ((l & 7) << 4);
    const int bbase = (brow * 64 + ((l >> 4) * 16)) ^ ((l & 7) << 4);

    auto STAGE = [&](int buf, int t) {
        const size_t tb = (size_t)t * 8192;
        #pragma unroll
        for (int p = 0; p < 4; ++p)
            #pragma unroll
            for (int i = 0; i < 2; ++i) {
                const int chunk = w * 2 + i;
                gload_lds16(gsrc[p] + tb + chunk * 1024 + l * 16,
                            smem + buf * 32768 + p * 8192 + chunk * 1024);
            }
    };

    f32x4 acc[4][4];
    #pragma unroll
    for (int i = 0; i < 4; ++i)
        #pragma unroll
        for (int j = 0; j < 4; ++j) acc[i][j] = (f32x4){0.f, 0.f, 0.f, 0.f};

    STAGE(0, 0);
    asm volatile("s_waitcnt vmcnt(0)" ::: "memory");
    __syncthreads();

    int cur = 0;
    for (int t = 0; t < NT; ++t) {
        if (t + 1 < NT) STAGE(cur ^ 1, t + 1);   // loads fly across the MFMA phase

        const char* sb = smem + cur * 32768;
        s16x8 ah[4], bh[4];
        #pragma unroll
        for (int i = 0; i < 4; ++i) ah[i] = *(const s16x8*)(sb + abase + i * 1024);
        #pragma unroll
        for (int j = 0; j < 4; ++j) bh[j] = *(const s16x8*)(sb + 16384 + bbase + j * 1024);
        #pragma unroll
        for (int i = 0; i < 4; ++i)
            #pragma unroll
            for (int j = 0; j < 4; ++j)
                acc[i][j] = __builtin_amdgcn_mfma_f32_16x16x32_bf16(ah[i], bh[j], acc[i][j], 0, 0, 0);

        s16x8 al[4];
        #pragma unroll
        for (int i = 0; i < 4; ++i) al[i] = *(const s16x8*)(sb + 8192 + abase + i * 1024);
        #pragma unroll
        for (int i = 0; i < 4; ++i)
            #pragma unroll
            for (int j = 0; j < 4; ++j)
                acc[i][j] = __builtin_amdgcn_mfma_f32_16x16x32_bf16(al[i], bh[j], acc[i][j], 0, 0, 0);

        s16x8 bl[4];
        #pragma unroll
        for (int j = 0; j < 4; ++j) bl[j] = *(const s16x8*)(sb + 24576 + bbase + j * 1024);
        #pragma unroll
        for (int i = 0; i < 4; ++i)
            #pragma unroll
            for (int j = 0; j < 4; ++j)
                acc[i][j] = __builtin_amdgcn_mfma_f32_16x16x32_bf16(ah[i], bl[j], acc[i][j], 0, 0, 0);

        if (t + 1 < NT) {
            asm volatile("s_waitcnt vmcnt(0)" ::: "memory");
            __syncthreads();
            cur ^= 1;
        }
    }

    // ---- epilogue: d = (xn + en) - 2*dot ; C/D map: col=lane&15, row=(lane>>4)*4+q
    // For fixed (i,q) the row's 64 columns live in one 16-lane group (j x lc).
    const int lr = (l >> 4) * 4;
    const int lc = l & 15;
    const int halfid = nt * 2 + wx;              // 0..63 column-half id
    float en_r[4];
    #pragma unroll
    for (int j = 0; j < 4; ++j) en_r[j] = enorm[colbase + n0 + wx * 64 + j * 16 + lc];
    #pragma unroll
    for (int i = 0; i < 4; ++i) {
        #pragma unroll
        for (int q = 0; q < 4; ++q) {
            const int gm = m0 + wy * 64 + i * 16 + lr + q;
            const float xnv = xnorm[gm];
            float* o = dist + (long long)gm * KOUT + colbase + n0 + wx * 64 + lc;
            float tv0 = FMAXV, tv1 = FMAXV, tv2 = FMAXV;
            int   ti0 = 0x7fffffff, ti1 = 0x7fffffff, ti2 = 0x7fffffff;
            #pragma unroll
            for (int j = 0; j < 4; ++j) {
                const float dv = (xnv + en_r[j]) - 2.0f * acc[i][j][q];
                o[j * 16] = dv;                   // scalar: dist base is 4B-aligned only
                ins3(dv, n0 + wx * 64 + j * 16 + lc, tv0, ti0, tv1, ti1, tv2, ti2);
            }
            #pragma unroll
            for (int off = 8; off > 0; off >>= 1) {   // merge within 16-lane group
                float w0 = __shfl_down(tv0, off), w1 = __shfl_down(tv1, off), w2 = __shfl_down(tv2, off);
                int   j0 = __shfl_down(ti0, off), j1 = __shfl_down(ti1, off), j2 = __shfl_down(ti2, off);
                ins3(w0, j0, tv0, ti0, tv1, ti1, tv2, ti2);
                ins3(w1, j1, tv0, ti0, tv1, ti1, tv2, ti2);
                ins3(w2, j2, tv0, ti0, tv1, ti1, tv2, ti2);
            }
            if (lc == 0) {
                const long long pb = ((long long)gm * 64 + halfid) * 3;
                pval[pb + 0] = tv0; pval[pb + 1] = tv1; pval[pb + 2] = tv2;
                pidx[pb + 0] = ti0; pidx[pb + 1] = ti1; pidx[pb + 2] = ti2;
            }
        }
    }

    // ---- fused pad: this block's mirror 128x128 stripe in the other codebook's half
    const int padbase = (mt == 0) ? KCB : 0;
    for (int r2 = w; r2 < 128; r2 += 4) {
        float* p = dist + (long long)(m0 + r2) * KOUT + padbase + n0;
        p[l] = PADV; p[l + 64] = PADV;
    }
}

// ---------------- top-3 merge: 64 sorted per-half partials -> final --------
__global__ __launch_bounds__(256)
void topk_merge_kernel(const float* __restrict__ pval,
                       const int* __restrict__ pidx,
                       int* __restrict__ idxbuf,
                       float* __restrict__ out,
                       float* __restrict__ counts) {
    int row = blockIdx.x * 4 + (threadIdx.x >> 6);
    if (row >= NROWS) return;
    const int lane = threadIdx.x & 63;
    const int colbase = (row < NCL) ? 0 : KCB;
    const long long pb = ((long long)row * 64 + lane) * 3;
    float v0 = pval[pb + 0], v1 = pval[pb + 1], v2 = pval[pb + 2];
    int   i0 = pidx[pb + 0], i1 = pidx[pb + 1], i2 = pidx[pb + 2];
    #pragma unroll
    for (int off = 32; off > 0; off >>= 1) {
        float w0 = __shfl_down(v0, off), w1 = __shfl_down(v1, off), w2 = __shfl_down(v2, off);
        int   j0 = __shfl_down(i0, off), j1 = __shfl_down(i1, off), j2 = __shfl_down(i2, off);
        ins3(w0, j0, v0, i0, v1, i1, v2, i2);
        ins3(w1, j1, v0, i0, v1, i1, v2, i2);
        ins3(w2, j2, v0, i0, v1, i1, v2, i2);
    }
    if (lane == 0) {
        long long rt = (long long)row * TK;
        idxbuf[rt + 0] = i0; idxbuf[rt + 1] = i1; idxbuf[rt + 2] = i2;
        out[ENC_OFF + rt + 0] = (float)(i0 + colbase);
        out[ENC_OFF + rt + 1] = (float)(i1 + colbase);
        out[ENC_OFF + rt + 2] = (float)(i2 + colbase);
        atomicAdd(&counts[i0 + colbase], 1.0f);
        atomicAdd(&counts[i1 + colbase], 1.0f);
        atomicAdd(&counts[i2 + colbase], 1.0f);
    }
}

// ---------------- gather + q_st + per-row SSE partial (no atomics) ----------------
__global__ __launch_bounds__(192)
void gather_kernel(const float* __restrict__ X,
                   const float* __restrict__ CE,
                   const float* __restrict__ FE,
                   const int* __restrict__ idxbuf,
                   float* __restrict__ out,
                   float* __restrict__ partials) {
    const int row = blockIdx.x;            // 0..25215
    const int tid = threadIdx.x;           // 0..191: one float4 column of the row
    const float4 xv = ((const float4*)(X + (size_t)row * C))[tid];
    const float* Ebase = (row < NCL) ? CE : FE;
    const long long rt0 = (long long)row * TK;
    float s = 0.f;
    #pragma unroll
    for (int t = 0; t < TK; ++t) {
        const int id = idxbuf[rt0 + t];
        const float4 ev = ((const float4*)(Ebase + (size_t)id * C))[tid];
        const float d0 = ev.x - xv.x, d1 = ev.y - xv.y, d2 = ev.z - xv.z, d3 = ev.w - xv.w;
        s += d0*d0 + d1*d1 + d2*d2 + d3*d3;
        // q_st = x + (quant - x), exactly the reference's float ops.
        float* q = out + QUANT_OFF + (rt0 + t) * C + tid * 4;
        q[0] = xv.x + d0; q[1] = xv.y + d1; q[2] = xv.z + d2; q[3] = xv.w + d3;
    }
    #pragma unroll
    for (int o = 32; o > 0; o >>= 1) s += __shfl_down(s, o);
    __shared__ float red[3];
    const int lane = tid & 63, w = tid >> 6;
    if (lane == 0) red[w] = s;
    __syncthreads();
    if (tid == 0) partials[row] = red[0] + red[1] + red[2];
}

// ---------------- finalize: avg_probs, perplexity, loss ----------------
__global__ void finalize_kernel(const float* __restrict__ counts,
                                const float* __restrict__ partials,
                                float* __restrict__ out) {
    __shared__ float  red[2][4];
    __shared__ double redd[2][4];
    int tid = threadIdx.x, lane = tid & 63, w = tid >> 6;
    float ecl = 0.f, eft = 0.f;
    for (int i = tid; i < KCB; i += blockDim.x) {
        float p = counts[i] * (1.0f / 128.0f);
        out[CLAVG_OFF + i] = p;
        ecl += p * logf(p + 1e-10f);
        float qv = counts[KCB + i] * (1.0f / 25088.0f);
        out[FTAVG_OFF + i] = qv;
        eft += qv * logf(qv + 1e-10f);
    }
    double scl = 0.0, sft = 0.0;
    for (int i = tid; i < NROWS; i += blockDim.x) {
        double v = (double)partials[i];
        if (i < NCL) scl += v; else sft += v;
    }
    for (int o = 32; o > 0; o >>= 1) {
        ecl += __shfl_down(ecl, o); eft += __shfl_down(eft, o);
        scl += __shfl_down(scl, o); sft += __shfl_down(sft, o);
    }
    if (lane == 0) { red[0][w] = ecl; red[1][w] = eft; redd[0][w] = scl; redd[1][w] = sft; }
    __syncthreads();
    if (tid == 0) {
        float tcl = red[0][0] + red[0][1] + red[0][2] + red[0][3];
        float tft = red[1][0] + red[1][1] + red[1][2] + red[1][3];
        double dcl = redd[0][0] + redd[0][1] + redd[0][2] + redd[0][3];
        double dft = redd[1][0] + redd[1][1] + redd[1][2] + redd[1][3];
        out[CLPERP_OFF] = expf(-tcl);
        out[FTPERP_OFF] = expf(-tft);
        float cl_loss = 0.25f * (float)(dcl / 294912.0);     // 1*128*3*768
        float ft_loss = 0.25f * (float)(dft / 57802752.0);   // 196*128*3*768
        out[0] = ft_loss + cl_loss;
    }
}

extern "C" void kernel_launch(void* const* d_in, const int* in_sizes, int n_in,
                              void* d_out, int out_size, void* d_ws, size_t ws_size,
                              hipStream_t stream) {
    const float* X  = (const float*)d_in[0];
    const float* CE = (const float*)d_in[1];
    const float* FE = (const float*)d_in[2];
    float* out = (float*)d_out;

    float* ws_f   = (float*)d_ws;
    float* xnorm  = ws_f;                         // 25216 (reused as SSE partials)
    float* enorm  = ws_f + NROWS;                 // 8192
    float* counts = ws_f + NROWS + KOUT;          // 8192
    int*   idxbuf = (int*)(ws_f + NROWS + 2 * KOUT);  // 75648 ints
    float* ssepart = xnorm;                       // xnorm dead after gemm; reuse
    float* dist   = out + DIST_OFF;

    // scratch inside the quant output region (dead until gather):
    // bf16 planes (102.6 MB) + top-3 partials (38.7 MB) < 232 MB
    short* XsH = (short*)(out + 4);
    short* XsL = XsH + XS_ELE;
    short* EsH = XsL + XS_ELE;
    short* EsL = EsH + ES_ELE;
    float* pval = (float*)(EsL + ES_ELE);         // 16B-aligned (all plane sizes %16==0)
    int*   pidx = (int*)(pval + PV_ELE);

    init_kernel<<<32, 256, 0, stream>>>(counts);
    norms_kernel<<<(NROWS + 2 * KCB) / 4, 256, 0, stream>>>(X, CE, FE, xnorm, enorm);
    presplit_kernel<<<MT * NT + 2 * NTL * NT, 256, 0, stream>>>(X, CE, FE, XsH, XsL, EsH, EsL);
    gemm_dist_kernel<<<dim3(NTL, MT), 256, 0, stream>>>(XsH, XsL, EsH, EsL, xnorm, enorm,
                                                        dist, pval, pidx);
    topk_merge_kernel<<<NROWS / 4, 256, 0, stream>>>(pval, pidx, idxbuf, out, counts);
    gather_kernel<<<NROWS, 192, 0, stream>>>(X, CE, FE, idxbuf, out, ssepart);
    finalize_kernel<<<1, 256, 0, stream>>>(counts, ssepart, out);
}

// Round 6
// 1758.682 us; speedup vs baseline: 1.9287x; 1.9287x over previous
//
#include <hip/hip_runtime.h>
#include <math.h>

#define DEVFN __device__ __forceinline__

typedef short  s16x8 __attribute__((ext_vector_type(8)));
typedef float  f32x4 __attribute__((ext_vector_type(4)));

constexpr int C     = 768;
constexpr int NROWS = 25216;   // 197*128
constexpr int NCL   = 128;     // class rows (features[0:1])
constexpr int KCB   = 4096;    // codes per codebook
constexpr int KOUT  = 8192;    // distance columns (class | feat)
constexpr int TK    = 3;
constexpr int NT    = 24;      // K-steps (768/32)
constexpr int MT    = 197;     // row tiles
constexpr int NTL   = 32;      // col tiles per codebook

// output layout (flat, return order)
constexpr long long QUANT_OFF  = 1;
constexpr long long QUANT_SZ   = (long long)NROWS * TK * C;         // 58,097,664
constexpr long long CLPERP_OFF = QUANT_OFF + QUANT_SZ;
constexpr long long FTPERP_OFF = CLPERP_OFF + 1;
constexpr long long CLAVG_OFF  = FTPERP_OFF + 1;
constexpr long long FTAVG_OFF  = CLAVG_OFF + KCB;
constexpr long long ENC_OFF    = FTAVG_OFF + KCB;
constexpr long long DIST_OFF   = ENC_OFF + (long long)NROWS * TK;   // 58,181,507
// DIST byte offset mod 16 == 12  ->  column k==1 of every row is 16B-aligned.

// packed pre-split bf16 scratch (lives in the quant output region, which is
// written only later by gather_kernel; 103 MB needed, 232 MB available)
constexpr size_t XS_ELE = (size_t)MT * NT * 4096;       // 19,365,888 bf16 per plane
constexpr size_t ES_ELE = (size_t)2 * NTL * NT * 4096;  //  6,291,456 bf16 per plane

constexpr float FMAXV = 3.4028234663852886e38f;
// Padding value: largest float that stays FINITE through a bf16 round-trip
// (0x7F7F0000). FLT_MAX rounds to +inf in bf16 -> inf-inf = nan in the
// harness compare.
constexpr float PADV  = 3.3895313892515355e38f;

DEVFN void gload_lds16(const void* g, void* l) {
    __builtin_amdgcn_global_load_lds(
        (const __attribute__((address_space(1))) unsigned*)g,
        (__attribute__((address_space(3))) unsigned*)l, 16, 0, 0);
}

// ---------------- top-3 primitives (BRANCHLESS: cndmask, no divergence) ----
DEVFN bool better(float v, int i, float bv, int bi) {
    return (v < bv) | ((v == bv) & (i < bi));  // stable: smaller index wins ties
}
DEVFN void ins3(float v, int i, float& v0, int& i0, float& v1, int& i1, float& v2, int& i2) {
    const bool b0 = better(v, i, v0, i0);
    const bool b1 = better(v, i, v1, i1);
    const bool b2 = better(v, i, v2, i2);
    // sorted invariant (v0<=v1<=v2 in 'better' order) gives b0 => b1 => b2
    const float nv1 = b0 ? v0 : (b1 ? v : v1);
    const int   ni1 = b0 ? i0 : (b1 ? i : i1);
    const float nv2 = b1 ? v1 : (b2 ? v : v2);
    const int   ni2 = b1 ? i1 : (b2 ? i : i2);
    v0 = b0 ? v : v0;  i0 = b0 ? i : i0;
    v1 = nv1;          i1 = ni1;
    v2 = nv2;          i2 = ni2;
}

// ---------------- init ----------------
__global__ void init_kernel(float* counts) {
    int i = blockIdx.x * blockDim.x + threadIdx.x;
    if (i < KOUT) counts[i] = 0.0f;
}

// ---------------- row norms (features + both codebooks) ----------------
__global__ void norms_kernel(const float* __restrict__ X,
                             const float* __restrict__ CE,
                             const float* __restrict__ FE,
                             float* __restrict__ xnorm,
                             float* __restrict__ enorm) {
    int row  = blockIdx.x * 4 + (threadIdx.x >> 6);
    int lane = threadIdx.x & 63;
    const int TOT = NROWS + 2 * KCB;
    if (row >= TOT) return;
    const float* src; float* dst;
    if (row < NROWS) { src = X + (long long)row * C; dst = xnorm + row; }
    else {
        int r = row - NROWS;
        src = (r < KCB) ? (CE + (long long)r * C) : (FE + (long long)(r - KCB) * C);
        dst = enorm + r;   // [0..4095] class, [4096..8191] feat
    }
    const float4* p = (const float4*)src;
    float s = 0.f;
    for (int j = lane; j < C / 4; j += 64) {
        float4 v = p[j];
        s += v.x*v.x + v.y*v.y + v.z*v.z + v.w*v.w;
    }
    for (int o = 32; o > 0; o >>= 1) s += __shfl_down(s, o);
    if (lane == 0) *dst = s;
}

// ---------------- pre-split: fp32 -> packed swizzled bf16 hi/lo tiles ------
__global__ __launch_bounds__(256)
void presplit_kernel(const float* __restrict__ X,
                     const float* __restrict__ CE,
                     const float* __restrict__ FE,
                     short* __restrict__ XsH, short* __restrict__ XsL,
                     short* __restrict__ EsH, short* __restrict__ EsL) {
    const int b = blockIdx.x;                    // 0..(197*24 + 2*32*24 - 1)
    const float* src; char* dH; char* dL;
    if (b < MT * NT) {
        const int tile = b / NT, ks = b % NT;
        src = X + (size_t)tile * 128 * C + ks * 32;
        dH = (char*)(XsH + (size_t)b * 4096);
        dL = (char*)(XsL + (size_t)b * 4096);
    } else {
        const int bb = b - MT * NT;              // 0..1535
        const int book = bb / (NTL * NT);
        const int rem  = bb % (NTL * NT);
        const int tile = rem / NT, ks = rem % NT;
        src = (book ? FE : CE) + (size_t)tile * 128 * C + ks * 32;
        dH = (char*)(EsH + (size_t)bb * 4096);
        dL = (char*)(EsL + (size_t)bb * 4096);
    }
    const int tid = threadIdx.x;
    const int row = tid >> 2, oc = tid & 3;      // rows {row, row+64}, k-octet oc
    #pragma unroll
    for (int rr = 0; rr < 2; ++rr) {
        const int r = row + rr * 64;
        const float* s = src + (size_t)r * C + oc * 8;
        float4 v0 = *(const float4*)s;
        float4 v1 = *(const float4*)(s + 4);
        float f[8] = {v0.x, v0.y, v0.z, v0.w, v1.x, v1.y, v1.z, v1.w};
        s16x8 hi, lo;
        #pragma unroll
        for (int q = 0; q < 8; ++q) {
            unsigned u = __float_as_uint(f[q]);
            hi[q] = (short)(u >> 16);
            lo[q] = (short)(__float_as_uint(f[q] - __uint_as_float(u & 0xffff0000u)) >> 16);
        }
        const int off = (r * 64 + oc * 16) ^ ((r & 7) << 4);
        *(s16x8*)(dH + off) = hi;
        *(s16x8*)(dL + off) = lo;
    }
}

// ---------------- distance GEMM via bf16x3 MFMA, global_load_lds pipeline --
// (round-4 version: dist + pad only; top-3 stays a separate kernel)
__global__ __launch_bounds__(256)
void gemm_dist_kernel(const short* __restrict__ XsH, const short* __restrict__ XsL,
                      const short* __restrict__ EsH, const short* __restrict__ EsL,
                      const float* __restrict__ xnorm,
                      const float* __restrict__ enorm,
                      float* __restrict__ dist) {
    __shared__ __align__(16) char smem[2 * 4 * 8192];   // [buf][plane][8KB]

    // XCD-aware bijective swizzle: 6304 blocks, 6304 % 8 == 0, chunk = 788
    const int orig = blockIdx.y * gridDim.x + blockIdx.x;
    const int wg   = (orig & 7) * 788 + (orig >> 3);
    const int mt = wg >> 5, nt = wg & 31;

    const int m0 = mt * 128, n0 = nt * 128;
    const int colbase = (mt == 0) ? 0 : KCB;
    const int btile = ((mt == 0) ? 0 : NTL) + nt;
    const int tid = threadIdx.x, l = tid & 63, w = tid >> 6;
    const int wy = w >> 1, wx = w & 1;

    const char* gsrc[4] = {
        (const char*)XsH + (size_t)mt * NT * 8192,
        (const char*)XsL + (size_t)mt * NT * 8192,
        (const char*)EsH + (size_t)btile * NT * 8192,
        (const char*)EsL + (size_t)btile * NT * 8192
    };

    // fragment geometry: wave (wy,wx) owns a 64x64 sub-tile
    const int arow = wy * 64 + (l & 15);
    const int brow = wx * 64 + (l & 15);
    const int abase = (arow * 64 + ((l >> 4) * 16)) ^ ((l & 7) << 4);
    const int bbase = (brow * 64 + ((l >> 4) * 16)) ^ ((l & 7) << 4);

    auto STAGE = [&](int buf, int t) {
        const size_t tb = (size_t)t * 8192;
        #pragma unroll
        for (int p = 0; p < 4; ++p)
            #pragma unroll
            for (int i = 0; i < 2; ++i) {
                const int chunk = w * 2 + i;
                gload_lds16(gsrc[p] + tb + chunk * 1024 + l * 16,
                            smem + buf * 32768 + p * 8192 + chunk * 1024);
            }
    };

    f32x4 acc[4][4];
    #pragma unroll
    for (int i = 0; i < 4; ++i)
        #pragma unroll
        for (int j = 0; j < 4; ++j) acc[i][j] = (f32x4){0.f, 0.f, 0.f, 0.f};

    STAGE(0, 0);
    asm volatile("s_waitcnt vmcnt(0)" ::: "memory");
    __syncthreads();

    int cur = 0;
    for (int t = 0; t < NT; ++t) {
        if (t + 1 < NT) STAGE(cur ^ 1, t + 1);   // loads fly across the MFMA phase

        const char* sb = smem + cur * 32768;
        s16x8 ah[4], bh[4];
        #pragma unroll
        for (int i = 0; i < 4; ++i) ah[i] = *(const s16x8*)(sb + abase + i * 1024);
        #pragma unroll
        for (int j = 0; j < 4; ++j) bh[j] = *(const s16x8*)(sb + 16384 + bbase + j * 1024);
        #pragma unroll
        for (int i = 0; i < 4; ++i)
            #pragma unroll
            for (int j = 0; j < 4; ++j)
                acc[i][j] = __builtin_amdgcn_mfma_f32_16x16x32_bf16(ah[i], bh[j], acc[i][j], 0, 0, 0);

        s16x8 al[4];
        #pragma unroll
        for (int i = 0; i < 4; ++i) al[i] = *(const s16x8*)(sb + 8192 + abase + i * 1024);
        #pragma unroll
        for (int i = 0; i < 4; ++i)
            #pragma unroll
            for (int j = 0; j < 4; ++j)
                acc[i][j] = __builtin_amdgcn_mfma_f32_16x16x32_bf16(al[i], bh[j], acc[i][j], 0, 0, 0);

        s16x8 bl[4];
        #pragma unroll
        for (int j = 0; j < 4; ++j) bl[j] = *(const s16x8*)(sb + 24576 + bbase + j * 1024);
        #pragma unroll
        for (int i = 0; i < 4; ++i)
            #pragma unroll
            for (int j = 0; j < 4; ++j)
                acc[i][j] = __builtin_amdgcn_mfma_f32_16x16x32_bf16(ah[i], bl[j], acc[i][j], 0, 0, 0);

        if (t + 1 < NT) {
            asm volatile("s_waitcnt vmcnt(0)" ::: "memory");
            __syncthreads();
            cur ^= 1;
        }
    }

    // ---- epilogue: d = (xn + en) - 2*dot ; C/D map: col=lane&15, row=(lane>>4)*4+q
    const int lr = (l >> 4) * 4;
    const int lc = l & 15;
    float en_r[4];
    #pragma unroll
    for (int j = 0; j < 4; ++j) en_r[j] = enorm[colbase + n0 + wx * 64 + j * 16 + lc];
    #pragma unroll
    for (int i = 0; i < 4; ++i) {
        #pragma unroll
        for (int q = 0; q < 4; ++q) {
            const int gm = m0 + wy * 64 + i * 16 + lr + q;
            const float xnv = xnorm[gm];
            float* o = dist + (long long)gm * KOUT + colbase + n0 + wx * 64 + lc;
            #pragma unroll
            for (int j = 0; j < 4; ++j)
                o[j * 16] = (xnv + en_r[j]) - 2.0f * acc[i][j][q];  // scalar: dist base is 4B-aligned only
        }
    }

    // ---- fused pad: this block's mirror 128x128 stripe in the other codebook's half
    const int padbase = (mt == 0) ? KCB : 0;
    for (int r2 = w; r2 < 128; r2 += 4) {
        float* p = dist + (long long)(m0 + r2) * KOUT + padbase + n0;
        p[l] = PADV; p[l + 64] = PADV;
    }
}

// ---------------- top-3: branchless, batched 8-deep loads ----------------
// dist byte offset ≡ 12 (mod 16) -> col 1 of every row is 16B-aligned:
// cols 1..4092 as 1023 aligned float4 (two phases of 8 batched loads/lane),
// tail {0,4093,4094,4095} scalar. Rows in REVERSE for LLC-tail locality.
__global__ __launch_bounds__(256)
void topk_kernel(const float* __restrict__ dist,
                 int* __restrict__ idxbuf,
                 float* __restrict__ out,
                 float* __restrict__ counts) {
    int rb = blockIdx.x * 4 + (threadIdx.x >> 6);
    if (rb >= NROWS) return;
    const int row = NROWS - 1 - rb;
    const int lane = threadIdx.x & 63;
    const int colbase = (row < NCL) ? 0 : KCB;
    const float* d = dist + (long long)row * KOUT + colbase;
    float v0 = FMAXV, v1 = FMAXV, v2 = FMAXV;
    int   i0 = 0x7fffffff, i1 = 0x7fffffff, i2 = 0x7fffffff;

    const float4* dv = (const float4*)(d + 1);   // 1023 aligned vectors

    // phase A: vectors 0..511 (8 batched dep-free loads, then process)
    float4 b[8];
    #pragma unroll
    for (int it = 0; it < 8; ++it) b[it] = dv[it * 64 + lane];
    #pragma unroll
    for (int it = 0; it < 8; ++it) {
        const int k = 1 + (it * 64 + lane) * 4;
        ins3(b[it].x, k,     v0, i0, v1, i1, v2, i2);
        ins3(b[it].y, k + 1, v0, i0, v1, i1, v2, i2);
        ins3(b[it].z, k + 2, v0, i0, v1, i1, v2, i2);
        ins3(b[it].w, k + 3, v0, i0, v1, i1, v2, i2);
    }
    // phase B: vectors 512..1022 (7 unguarded + 1 guarded)
    #pragma unroll
    for (int it = 0; it < 7; ++it) b[it] = dv[(8 + it) * 64 + lane];
    const bool hasLast = (960 + lane) < 1023;
    b[7] = hasLast ? dv[960 + lane]
                   : (float4){FMAXV, FMAXV, FMAXV, FMAXV};
    #pragma unroll
    for (int it = 0; it < 7; ++it) {
        const int k = 1 + ((8 + it) * 64 + lane) * 4;
        ins3(b[it].x, k,     v0, i0, v1, i1, v2, i2);
        ins3(b[it].y, k + 1, v0, i0, v1, i1, v2, i2);
        ins3(b[it].z, k + 2, v0, i0, v1, i1, v2, i2);
        ins3(b[it].w, k + 3, v0, i0, v1, i1, v2, i2);
    }
    {
        const int k = 1 + (960 + lane) * 4;      // idx harmless when masked (v=FMAXV, i big? )
        const int kk = hasLast ? k : 0x7ffffff0; // keep masked entries maximal in tie-order
        ins3(b[7].x, kk,     v0, i0, v1, i1, v2, i2);
        ins3(b[7].y, kk + 1, v0, i0, v1, i1, v2, i2);
        ins3(b[7].z, kk + 2, v0, i0, v1, i1, v2, i2);
        ins3(b[7].w, kk + 3, v0, i0, v1, i1, v2, i2);
    }
    if (lane < 4) {                              // cols 0, 4093, 4094, 4095
        const int k = (lane == 0) ? 0 : 4092 + lane;
        ins3(d[k], k, v0, i0, v1, i1, v2, i2);
    }

    #pragma unroll
    for (int off = 32; off > 0; off >>= 1) {
        float w0 = __shfl_down(v0, off), w1 = __shfl_down(v1, off), w2 = __shfl_down(v2, off);
        int   j0 = __shfl_down(i0, off), j1 = __shfl_down(i1, off), j2 = __shfl_down(i2, off);
        ins3(w0, j0, v0, i0, v1, i1, v2, i2);
        ins3(w1, j1, v0, i0, v1, i1, v2, i2);
        ins3(w2, j2, v0, i0, v1, i1, v2, i2);
    }
    if (lane == 0) {
        long long rt = (long long)row * TK;
        idxbuf[rt + 0] = i0; idxbuf[rt + 1] = i1; idxbuf[rt + 2] = i2;
        out[ENC_OFF + rt + 0] = (float)(i0 + colbase);
        out[ENC_OFF + rt + 1] = (float)(i1 + colbase);
        out[ENC_OFF + rt + 2] = (float)(i2 + colbase);
        atomicAdd(&counts[i0 + colbase], 1.0f);
        atomicAdd(&counts[i1 + colbase], 1.0f);
        atomicAdd(&counts[i2 + colbase], 1.0f);
    }
}

// ---------------- gather + q_st + per-row SSE partial (no atomics) ----------------
__global__ __launch_bounds__(192)
void gather_kernel(const float* __restrict__ X,
                   const float* __restrict__ CE,
                   const float* __restrict__ FE,
                   const int* __restrict__ idxbuf,
                   float* __restrict__ out,
                   float* __restrict__ partials) {
    const int row = blockIdx.x;            // 0..25215
    const int tid = threadIdx.x;           // 0..191: one float4 column of the row
    const float4 xv = ((const float4*)(X + (size_t)row * C))[tid];
    const float* Ebase = (row < NCL) ? CE : FE;
    const long long rt0 = (long long)row * TK;
    float s = 0.f;
    #pragma unroll
    for (int t = 0; t < TK; ++t) {
        const int id = idxbuf[rt0 + t];
        const float4 ev = ((const float4*)(Ebase + (size_t)id * C))[tid];
        const float d0 = ev.x - xv.x, d1 = ev.y - xv.y, d2 = ev.z - xv.z, d3 = ev.w - xv.w;
        s += d0*d0 + d1*d1 + d2*d2 + d3*d3;
        // q_st = x + (quant - x), exactly the reference's float ops.
        float* q = out + QUANT_OFF + (rt0 + t) * C + tid * 4;
        q[0] = xv.x + d0; q[1] = xv.y + d1; q[2] = xv.z + d2; q[3] = xv.w + d3;
    }
    #pragma unroll
    for (int o = 32; o > 0; o >>= 1) s += __shfl_down(s, o);
    __shared__ float red[3];
    const int lane = tid & 63, w = tid >> 6;
    if (lane == 0) red[w] = s;
    __syncthreads();
    if (tid == 0) partials[row] = red[0] + red[1] + red[2];
}

// ---------------- finalize: avg_probs, perplexity, loss ----------------
__global__ void finalize_kernel(const float* __restrict__ counts,
                                const float* __restrict__ partials,
                                float* __restrict__ out) {
    __shared__ float  red[2][4];
    __shared__ double redd[2][4];
    int tid = threadIdx.x, lane = tid & 63, w = tid >> 6;
    float ecl = 0.f, eft = 0.f;
    for (int i = tid; i < KCB; i += blockDim.x) {
        float p = counts[i] * (1.0f / 128.0f);
        out[CLAVG_OFF + i] = p;
        ecl += p * logf(p + 1e-10f);
        float qv = counts[KCB + i] * (1.0f / 25088.0f);
        out[FTAVG_OFF + i] = qv;
        eft += qv * logf(qv + 1e-10f);
    }
    double scl = 0.0, sft = 0.0;
    for (int i = tid; i < NROWS; i += blockDim.x) {
        double v = (double)partials[i];
        if (i < NCL) scl += v; else sft += v;
    }
    for (int o = 32; o > 0; o >>= 1) {
        ecl += __shfl_down(ecl, o); eft += __shfl_down(eft, o);
        scl += __shfl_down(scl, o); sft += __shfl_down(sft, o);
    }
    if (lane == 0) { red[0][w] = ecl; red[1][w] = eft; redd[0][w] = scl; redd[1][w] = sft; }
    __syncthreads();
    if (tid == 0) {
        float tcl = red[0][0] + red[0][1] + red[0][2] + red[0][3];
        float tft = red[1][0] + red[1][1] + red[1][2] + red[1][3];
        double dcl = redd[0][0] + redd[0][1] + redd[0][2] + redd[0][3];
        double dft = redd[1][0] + redd[1][1] + redd[1][2] + redd[1][3];
        out[CLPERP_OFF] = expf(-tcl);
        out[FTPERP_OFF] = expf(-tft);
        float cl_loss = 0.25f * (float)(dcl / 294912.0);     // 1*128*3*768
        float ft_loss = 0.25f * (float)(dft / 57802752.0);   // 196*128*3*768
        out[0] = ft_loss + cl_loss;
    }
}

extern "C" void kernel_launch(void* const* d_in, const int* in_sizes, int n_in,
                              void* d_out, int out_size, void* d_ws, size_t ws_size,
                              hipStream_t stream) {
    const float* X  = (const float*)d_in[0];
    const float* CE = (const float*)d_in[1];
    const float* FE = (const float*)d_in[2];
    float* out = (float*)d_out;

    float* ws_f   = (float*)d_ws;
    float* xnorm  = ws_f;                         // 25216 (reused as SSE partials)
    float* enorm  = ws_f + NROWS;                 // 8192
    float* counts = ws_f + NROWS + KOUT;          // 8192
    int*   idxbuf = (int*)(ws_f + NROWS + 2 * KOUT);  // 75648 ints
    float* ssepart = xnorm;                       // xnorm dead after gemm; reuse
    float* dist   = out + DIST_OFF;

    // packed bf16 scratch inside the quant output region (dead until gather)
    short* XsH = (short*)(out + 4);
    short* XsL = XsH + XS_ELE;
    short* EsH = XsL + XS_ELE;
    short* EsL = EsH + ES_ELE;

    init_kernel<<<32, 256, 0, stream>>>(counts);
    norms_kernel<<<(NROWS + 2 * KCB) / 4, 256, 0, stream>>>(X, CE, FE, xnorm, enorm);
    presplit_kernel<<<MT * NT + 2 * NTL * NT, 256, 0, stream>>>(X, CE, FE, XsH, XsL, EsH, EsL);
    gemm_dist_kernel<<<dim3(NTL, MT), 256, 0, stream>>>(XsH, XsL, EsH, EsL, xnorm, enorm, dist);
    topk_kernel<<<NROWS / 4, 256, 0, stream>>>(dist, idxbuf, out, counts);
    gather_kernel<<<NROWS, 192, 0, stream>>>(X, CE, FE, idxbuf, out, ssepart);
    finalize_kernel<<<1, 256, 0, stream>>>(counts, ssepart, out);
}